// Round 3
// baseline (339.683 us; speedup 1.0000x reference)
//
#include <hip/hip_runtime.h>
#include <hip/hip_bf16.h>
#include <stdint.h>

// Round 4: single-barrier-per-K-tile GEMM. R3's 4-phase structure serialized
// LDS-drain and MFMA behind 8 barriers/tile (MfmaUtil 30%). Now: per K-tile,
// load all 24 fragments (two K-half register sets) + issue 8 staging loads,
// then 64 MFMAs, then ONE counted vmcnt + ONE barrier. Compiler's fine-grained
// lgkmcnt waits overlap h1-fragment drain under h0 MFMAs; single barrier lets
// waves desync so ds_read and MFMA pipes co-schedule across waves (m114).
// T1 XCD swizzle, T2 LDS XOR swizzle, T4 counted vmcnt, T5 setprio retained.
//
// ws layout unchanged.

#define B_ 4
#define T_ 4096
#define C_ 1024
#define H_ 16
#define D_ 64
#define M_ (B_*T_)
#define TCH 512
#define K_ 1024
#define NT_ (K_/64)          // 16 K-tiles of BK=64

using u16 = unsigned short;
using u32 = unsigned int;

typedef __attribute__((ext_vector_type(8))) short bf16x8;
typedef __attribute__((ext_vector_type(4))) float f32x4;

static __device__ __forceinline__ u16 f2bf(float f){
  u32 u = __float_as_uint(f);
  u32 r = (u + 0x7fffu + ((u >> 16) & 1u)) >> 16;   // RNE, no NaN here
  return (u16)r;
}
static __device__ __forceinline__ void unpack8(uint4 u, float* f){
  f[0]=__uint_as_float(u.x<<16); f[1]=__uint_as_float(u.x&0xffff0000u);
  f[2]=__uint_as_float(u.y<<16); f[3]=__uint_as_float(u.y&0xffff0000u);
  f[4]=__uint_as_float(u.z<<16); f[5]=__uint_as_float(u.z&0xffff0000u);
  f[6]=__uint_as_float(u.w<<16); f[7]=__uint_as_float(u.w&0xffff0000u);
}
static __device__ __forceinline__ void gload16(const u16* g, u16* l){
  __builtin_amdgcn_global_load_lds(
      (const __attribute__((address_space(1))) void*)g,
      (__attribute__((address_space(3))) void*)l, 16, 0, 0);
}

#define FENCE() asm volatile("" ::: "memory")
#define BAR() do { FENCE(); __builtin_amdgcn_s_barrier(); FENCE(); } while(0)

// ---------------- fp32 -> bf16 convert --------------------------------------
__global__ __launch_bounds__(256) void cvt_f32_bf16(
    const float* __restrict__ src, u16* __restrict__ dst, int n)
{
  const int i = (blockIdx.x*256 + threadIdx.x) * 8;
  if (i >= n) return;
  const float4 a = *(const float4*)(src + i);
  const float4 b = *(const float4*)(src + i + 4);
  uint4 o;
  o.x = (u32)f2bf(a.x) | ((u32)f2bf(a.y) << 16);
  o.y = (u32)f2bf(a.z) | ((u32)f2bf(a.w) << 16);
  o.z = (u32)f2bf(b.x) | ((u32)f2bf(b.y) << 16);
  o.w = (u32)f2bf(b.z) | ((u32)f2bf(b.w) << 16);
  *(uint4*)(dst + i) = o;
}

// all four 1024x1024 weights in one launch (512 blocks per segment)
__global__ __launch_bounds__(256) void cvt_w4(
    const float* __restrict__ s0, const float* __restrict__ s1,
    const float* __restrict__ s2, const float* __restrict__ s3,
    u16* __restrict__ d0, u16* __restrict__ d1,
    u16* __restrict__ d2, u16* __restrict__ d3)
{
  const int seg = blockIdx.x >> 9;
  const int bi  = blockIdx.x & 511;
  const float* s = seg==0?s0:seg==1?s1:seg==2?s2:s3;
  u16*         d = seg==0?d0:seg==1?d1:seg==2?d2:d3;
  const int i = (bi*256 + threadIdx.x) * 8;
  const float4 a = *(const float4*)(s + i);
  const float4 b = *(const float4*)(s + i + 4);
  uint4 o;
  o.x = (u32)f2bf(a.x) | ((u32)f2bf(a.y) << 16);
  o.y = (u32)f2bf(a.z) | ((u32)f2bf(a.w) << 16);
  o.z = (u32)f2bf(b.x) | ((u32)f2bf(b.y) << 16);
  o.w = (u32)f2bf(b.z) | ((u32)f2bf(b.w) << 16);
  *(uint4*)(d + i) = o;
}

// ---------------- 256x256 / BK=64 / 1-barrier-per-tile MFMA GEMM -------------
// Y[M,N] = X[M,K] @ W[N,K]^T + b.  512 threads = 8 waves (2M x 4N), wave tile
// 128x64. LDS ring: slot s: [Al | Ah | Bl | Bh] 16 KB half-buffers
// (u16 offsets s*32768 + {0,8192,16384,24576}).
// T2 swizzle: logical 16B-chunk c of row r at phys chunk c^(r&7); staged via
// linear global_load_lds dest + inverse-swizzled global source.
// Per K-tile u: { rd h0 frags(12); stage A(u+1)(4); rd h1 frags(12);
//                 stage B(u+2)(4); setprio(1); 64 MFMA; setprio(0);
//                 vmcnt(4|0); BAR }.
// Hazards: WAR - stage(u+1)->s^1 safe: tile-(u-1) end-BAR follows all waves'
// reads of s^1 (MFMA consumption forces ds_read completion). RAW - tile-u
// reads need A(u) (staged u-1) & B(u) (staged u-2): vmcnt(4)+BAR at end of
// u-1 drains everything older than B(u+1).
template<bool FUSED>
__global__ __launch_bounds__(512, 2) void gemm256(
    const u16* __restrict__ X, const u16* __restrict__ Wm,
    const float* __restrict__ b0, const float* __restrict__ b1,
    const float* __restrict__ b2,
    void* __restrict__ Y0, void* __restrict__ Y1, void* __restrict__ Y2)
{
  extern __shared__ __align__(16) u16 lds[];   // 131072 B
  const int tid  = threadIdx.x;
  const int lane = tid & 63, w = tid >> 6;
  const int wr = w >> 2, wc = w & 3;           // wave grid 2 x 4
  const int fr = lane & 15, hi = lane >> 4;

  // T1: XCD-aware swizzle (gridDim.x % 8 == 0 here: 768 / 256)
  const int cpx = gridDim.x >> 3;
  const int lin = (blockIdx.x & 7)*cpx + (blockIdx.x >> 3);
  const int bm = lin & 63;                     // bm fastest: B-panel L2 reuse per XCD
  const int bn = lin >> 6;

  // staging: thread stages 2x16B per half-buffer, linear LDS dest tid*16 (+8192B)
  const int srow = tid >> 3;                   // 0..63
  const int scc  = (tid & 7) ^ (srow & 7);     // inverse-swizzled source chunk
  const u16* gA = X  + (size_t)(bm*256 + srow)*K_ + scc*8;
  const u16* gB = Wm + (size_t)(bn*256 + srow)*K_ + scc*8;
  u16* const ldst = lds + tid*8;

  auto stageA = [&](int s, int h, int kt){
    const u16* src = gA + (size_t)(h*128)*K_ + kt*64;
    u16* dst = ldst + s*32768 + h*8192;
    gload16(src, dst);
    gload16(src + (size_t)64*K_, dst + 4096);
  };
  auto stageB = [&](int s, int h, int kt){
    const u16* src = gB + (size_t)(h*128)*K_ + kt*64;
    u16* dst = ldst + s*32768 + 16384 + h*8192;
    gload16(src, dst);
    gload16(src + (size_t)64*K_, dst + 4096);
  };

  f32x4 acc[8][4] = {};
  const int cx0 = (hi ^ (fr & 7)) << 3;        // k-half 0 phys chunk (u16 offset)
  const int cx1 = ((4 + hi) ^ (fr & 7)) << 3;  // k-half 1 phys chunk
  const int br  = (wc & 1) * 64;               // B local row base

  // prologue, FIFO order: B(0)x4, A(0)x4, B(1)x4 -> vmcnt(4) drains B0,A0
  stageB(0,0,0); stageB(0,1,0);
  stageA(0,0,0); stageA(0,1,0);
  stageB(1,0,1); stageB(1,1,1);
  asm volatile("s_waitcnt vmcnt(4)" ::: "memory");
  BAR();

  #pragma unroll 2
  for (int u = 0; u < NT_; ++u) {
    const int s = u & 1;
    const u16* As = lds + s*32768 + wr*8192;
    const u16* Bs = lds + s*32768 + 16384 + (wc>>1)*8192;

    bf16x8 a0[8], a1[8], bv0[4], bv1[4];

    // K-half 0 fragments (12 ds_read_b128)
    #pragma unroll
    for (int j = 0; j < 4; ++j) bv0[j] = *(const bf16x8*)&Bs[(br + j*16 + fr)*64 + cx0];
    #pragma unroll
    for (int i = 0; i < 8; ++i) a0[i]  = *(const bf16x8*)&As[(i*16 + fr)*64 + cx0];

    if (u + 1 < NT_) { stageA(s^1, 0, u+1); stageA(s^1, 1, u+1); }

    // K-half 1 fragments (12 ds_read_b128) - drain under h0 MFMAs
    #pragma unroll
    for (int j = 0; j < 4; ++j) bv1[j] = *(const bf16x8*)&Bs[(br + j*16 + fr)*64 + cx1];
    #pragma unroll
    for (int i = 0; i < 8; ++i) a1[i]  = *(const bf16x8*)&As[(i*16 + fr)*64 + cx1];

    if (u + 2 < NT_) { stageB(s, 0, u+2); stageB(s, 1, u+2); }

    __builtin_amdgcn_s_setprio(1);
    #pragma unroll
    for (int i = 0; i < 8; ++i)
      #pragma unroll
      for (int j = 0; j < 4; ++j)
        acc[i][j] = __builtin_amdgcn_mfma_f32_16x16x32_bf16(a0[i], bv0[j], acc[i][j], 0, 0, 0);
    #pragma unroll
    for (int i = 0; i < 8; ++i)
      #pragma unroll
      for (int j = 0; j < 4; ++j)
        acc[i][j] = __builtin_amdgcn_mfma_f32_16x16x32_bf16(a1[i], bv1[j], acc[i][j], 0, 0, 0);
    __builtin_amdgcn_s_setprio(0);

    if (u + 1 < NT_) {
      if (u + 2 < NT_) asm volatile("s_waitcnt vmcnt(4)" ::: "memory");
      else             asm volatile("s_waitcnt vmcnt(0)" ::: "memory");
      BAR();
    }
  }

  // epilogue: C/D layout col = lane&15 (n), row = (lane>>4)*4 + reg (m).
  // j innermost: per (i,r) the wave's 4 stores cover one contiguous
  // 128B (bf16) / 256B (fp32) span -> full-line writes, no RMW.
  const int nloc = wc*64 + fr;
  if constexpr (FUSED) {
    const int sel  = bn >> 2;                  // uniform per block
    const int colb = (bn & 3)*256 + nloc;
    const float* bp = (sel == 0 ? b0 : sel == 1 ? b1 : b2);
    u16* Y = (u16*)(sel == 0 ? Y0 : sel == 1 ? Y1 : Y2);
    const bool elu = sel < 2;
    float bb[4];
    #pragma unroll
    for (int j = 0; j < 4; ++j) bb[j] = bp[colb + j*16];
    #pragma unroll
    for (int i = 0; i < 8; ++i) {
      #pragma unroll
      for (int r = 0; r < 4; ++r) {
        const size_t row = (size_t)(bm*256 + wr*128 + i*16 + hi*4 + r);
        u16* yp = Y + row*1024 + colb;
        #pragma unroll
        for (int j = 0; j < 4; ++j) {
          float v = acc[i][j][r] + bb[j];
          if (elu) v = (v > 0.0f) ? (v + 1.0f) : __expf(v);   // elu(x)+1
          yp[j*16] = f2bf(v);
        }
      }
    }
  } else {
    const int n0 = bn*256 + nloc;
    float bb[4];
    #pragma unroll
    for (int j = 0; j < 4; ++j) bb[j] = b0[n0 + j*16];
    float* Y = (float*)Y0;
    #pragma unroll
    for (int i = 0; i < 8; ++i) {
      #pragma unroll
      for (int r = 0; r < 4; ++r) {
        const size_t row = (size_t)(bm*256 + wr*128 + i*16 + hi*4 + r);
        float* yp = Y + row*1024 + n0;
        #pragma unroll
        for (int j = 0; j < 4; ++j)
          yp[j*16] = acc[i][j][r] + bb[j];
      }
    }
  }
}

// ---------------- kv partial / reduce / attn_norm: unchanged -------------------
__global__ __launch_bounds__(256) void kv_partial(
    const u16* __restrict__ Kb, const u16* __restrict__ Vb,
    float* __restrict__ kvp, float* __restrict__ ksp)
{
  const int tid = threadIdx.x;
  const int bh = blockIdx.x;
  const int b = bh >> 4, h = bh & 15;
  const int chunk = blockIdx.y;
  __shared__ float kbuf[32][68];
  __shared__ float vbuf[32][68];
  float acc[4][4] = {};
  float ksl = 0.0f;
  const int d0 = (tid >> 4) << 2, e0 = (tid & 15) << 2;
  const int lrow = tid >> 3, lcol = (tid & 7) << 3;

  for (int s = 0; s < TCH/32; ++s) {
    const int t = chunk*TCH + s*32;
    {
      const size_t base = ((size_t)(b*T_ + t + lrow))*C_ + h*64 + lcol;
      const uint4 ku = *(const uint4*)(Kb + base);
      const uint4 vu = *(const uint4*)(Vb + base);
      float kf[8], vf[8];
      unpack8(ku, kf); unpack8(vu, vf);
      #pragma unroll
      for (int j = 0; j < 8; ++j) { kbuf[lrow][lcol+j] = kf[j]; vbuf[lrow][lcol+j] = vf[j]; }
    }
    __syncthreads();
    if (tid < 64) {
      #pragma unroll
      for (int tt = 0; tt < 32; ++tt) ksl += kbuf[tt][tid];
    }
    #pragma unroll
    for (int tt = 0; tt < 32; ++tt) {
      const float4 ka = *(const float4*)&kbuf[tt][d0];
      const float4 va = *(const float4*)&vbuf[tt][e0];
      const float kr[4] = {ka.x, ka.y, ka.z, ka.w};
      const float vr[4] = {va.x, va.y, va.z, va.w};
      #pragma unroll
      for (int i = 0; i < 4; ++i)
        #pragma unroll
        for (int j = 0; j < 4; ++j)
          acc[i][j] = fmaf(kr[i], vr[j], acc[i][j]);
    }
    __syncthreads();
  }

  float* dst = kvp + ((size_t)(chunk*64 + bh))*4096;
  #pragma unroll
  for (int i = 0; i < 4; ++i)
    *(float4*)&dst[(d0+i)*64 + e0] = make_float4(acc[i][0], acc[i][1], acc[i][2], acc[i][3]);
  if (tid < 64) ksp[((size_t)(chunk*64 + bh))*64 + tid] = ksl;
}

__global__ __launch_bounds__(256) void kv_reduce(
    const float* __restrict__ kvp, const float* __restrict__ ksp,
    float* __restrict__ kv, float* __restrict__ ksum)
{
  const int idx = blockIdx.x*256 + threadIdx.x;
  if (idx < 64*64*64) {
    float s = 0.0f;
    #pragma unroll
    for (int c = 0; c < 8; ++c) s += kvp[(size_t)c*262144 + idx];
    kv[idx] = s;
  } else {
    const int i2 = idx - 262144;
    float s = 0.0f;
    #pragma unroll
    for (int c = 0; c < 8; ++c) s += ksp[(size_t)c*4096 + i2];
    ksum[i2] = s;
  }
}

__global__ __launch_bounds__(256) void attn_norm(
    const u16* __restrict__ Qb, const float* __restrict__ kv,
    const float* __restrict__ ksum, u16* __restrict__ attn)
{
  const int tid = threadIdx.x;
  const int bh = blockIdx.x;
  const int b = bh >> 4, h = bh & 15;
  const int t0 = blockIdx.y * 64;
  __shared__ float kvs[64][68];
  __shared__ float qs[64][68];
  __shared__ float kss[64];

  for (int i = tid; i < 1024; i += 256) {
    const int d = i >> 4, e4 = (i & 15) << 2;
    *(float4*)&kvs[d][e4] = *(const float4*)&kv[(size_t)bh*4096 + d*64 + e4];
  }
  if (tid < 64) kss[tid] = ksum[bh*64 + tid];
  for (int i = tid; i < 512; i += 256) {
    const int r = i >> 3, c8 = (i & 7) << 3;
    const uint4 qu = *(const uint4*)&Qb[((size_t)(b*T_ + t0 + r))*C_ + h*64 + c8];
    float qf[8]; unpack8(qu, qf);
    #pragma unroll
    for (int j = 0; j < 8; ++j) qs[r][c8+j] = qf[j];
  }
  __syncthreads();

  const int r0 = (tid >> 4) << 2, e0 = (tid & 15) << 2;
  float den[4];
  #pragma unroll
  for (int i = 0; i < 4; ++i) {
    float s = 0.0f;
    #pragma unroll
    for (int d = 0; d < 64; ++d) s = fmaf(qs[r0+i][d], kss[d], s);
    den[i] = fmaxf(s, 1e-6f);
  }
  float acc[4][4] = {};
  #pragma unroll
  for (int d = 0; d < 64; ++d) {
    const float4 kva = *(const float4*)&kvs[d][e0];
    const float kvr[4] = {kva.x, kva.y, kva.z, kva.w};
    #pragma unroll
    for (int i = 0; i < 4; ++i) {
      const float qv = qs[r0+i][d];
      #pragma unroll
      for (int j = 0; j < 4; ++j)
        acc[i][j] = fmaf(qv, kvr[j], acc[i][j]);
    }
  }
  #pragma unroll
  for (int i = 0; i < 4; ++i) {
    const float inv = 1.0f / den[i];
    uint2 o2;
    o2.x = (u32)f2bf(acc[i][0]*inv) | ((u32)f2bf(acc[i][1]*inv) << 16);
    o2.y = (u32)f2bf(acc[i][2]*inv) | ((u32)f2bf(acc[i][3]*inv) << 16);
    *(uint2*)&attn[((size_t)(b*T_ + t0 + r0 + i))*C_ + h*64 + e0] = o2;
  }
}

extern "C" void kernel_launch(void* const* d_in, const int* in_sizes, int n_in,
                              void* d_out, int out_size, void* d_ws, size_t ws_size,
                              hipStream_t stream)
{
  (void)in_sizes; (void)n_in; (void)out_size; (void)ws_size;
  const float* x  = (const float*)d_in[0];
  const float* Wq = (const float*)d_in[1];
  const float* bq = (const float*)d_in[2];
  const float* Wk = (const float*)d_in[3];
  const float* bk = (const float*)d_in[4];
  const float* Wv = (const float*)d_in[5];
  const float* bv = (const float*)d_in[6];
  const float* Wo = (const float*)d_in[7];
  const float* bo = (const float*)d_in[8];
  float* out = (float*)d_out;
  char* ws = (char*)d_ws;

  const size_t MB = 1024*1024;
  u16*   xb   = (u16*)(ws);                       // 32MB
  u16*   wqb  = (u16*)(ws + 32*MB);               // 2MB each; wq..wv = fused [3072,1024]
  u16*   wkb  = (u16*)(ws + 34*MB);
  u16*   wvb  = (u16*)(ws + 36*MB);
  u16*   wob  = (u16*)(ws + 38*MB);
  u16*   q    = (u16*)(ws + 40*MB);               // 32MB
  u16*   k    = (u16*)(ws + 72*MB);               // 32MB
  u16*   v    = (u16*)(ws + 104*MB);              // 32MB
  float* kvp  = (float*)(ws + 136*MB);            // 8MB
  float* ksp  = (float*)(ws + 144*MB);            // 128KB
  float* kv   = (float*)(ws + 144*MB + 131072);   // 1MB
  float* ksum = (float*)(ws + 145*MB + 131072);   // 16KB
  u16*   attn = xb;  // xb dead after the fused QKV GEMM

  static bool s_attr_done = false;
  if (!s_attr_done) {
    (void)hipFuncSetAttribute(reinterpret_cast<const void*>(gemm256<true>),
                              hipFuncAttributeMaxDynamicSharedMemorySize, 131072);
    (void)hipFuncSetAttribute(reinterpret_cast<const void*>(gemm256<false>),
                              hipFuncAttributeMaxDynamicSharedMemorySize, 131072);
    s_attr_done = true;
  }

  dim3 blk(256);
  cvt_f32_bf16<<<dim3(M_*C_/2048), blk, 0, stream>>>(x, xb, M_*C_);
  cvt_w4<<<dim3(2048), blk, 0, stream>>>(Wq, Wk, Wv, Wo, wqb, wkb, wvb, wob);

  // fused QKV projection: Y[16384, 3072] split into q/k/v, ELU+1 on q,k
  gemm256<true><<<dim3(64*12), dim3(512), 131072, stream>>>(
      xb, wqb, bq, bk, bv, q, k, v);

  kv_partial<<<dim3(B_*H_, T_/TCH), blk, 0, stream>>>(k, v, kvp, ksp);
  kv_reduce<<<dim3(1040), blk, 0, stream>>>(kvp, ksp, kv, ksum);
  attn_norm<<<dim3(B_*H_, T_/64), blk, 0, stream>>>(q, kv, ksum, attn);

  // output projection: fp32 out
  gemm256<false><<<dim3(64*4), dim3(512), 131072, stream>>>(
      attn, wob, bo, bo, bo, out, out, out);
}

// Round 4
// 226.784 us; speedup vs baseline: 1.4978x; 1.4978x over previous
//
#include <hip/hip_runtime.h>
#include <hip/hip_bf16.h>
#include <stdint.h>

// Round 5: revert GEMM to the proven R3 4-phase structure (280 us total; R4's
// barrier-collapse regressed per m196's coarse-split warning). New this round:
//  - attn_norm rewritten as MFMA (num = q @ kvT via 16x16x32; den folded in as
//    a 5th B-fragment built from a ksum row appended to kvT; bf16 kv/ksum adds
//    ~0.4% rel err ~ 5e-6 abs, << tolerance).
//  - kv_reduce now emits bf16 kvT[bh][80][64] (row 64 = ksum, rows 65-79 = 0).
//  - cvt kernels merged into one launch.
//
// ws layout (bytes):
//   xb   : [0, 32MB)  bf16 [M, C]   (reused as attn)
//   wqb  : 32MB + 2MB each: wkb, wvb, wob   (wq..wv contiguous = fused [3C, C])
//   q    : 40MB  k : 72MB  v : 104MB   bf16 [M, C]
//   kvp  : 136MB f32 [8][64][64][64];  ksp : +8MB f32 [8][64][64]
//   kvT  : 144MB+128KB  bf16 [64][80][64]  (640 KB)

#define B_ 4
#define T_ 4096
#define C_ 1024
#define H_ 16
#define D_ 64
#define M_ (B_*T_)
#define TCH 512
#define K_ 1024
#define NT_ (K_/64)          // 16 K-tiles of BK=64

using u16 = unsigned short;
using u32 = unsigned int;

typedef __attribute__((ext_vector_type(8))) short bf16x8;
typedef __attribute__((ext_vector_type(4))) float f32x4;

static __device__ __forceinline__ u16 f2bf(float f){
  u32 u = __float_as_uint(f);
  u32 r = (u + 0x7fffu + ((u >> 16) & 1u)) >> 16;   // RNE, no NaN here
  return (u16)r;
}
static __device__ __forceinline__ void unpack8(uint4 u, float* f){
  f[0]=__uint_as_float(u.x<<16); f[1]=__uint_as_float(u.x&0xffff0000u);
  f[2]=__uint_as_float(u.y<<16); f[3]=__uint_as_float(u.y&0xffff0000u);
  f[4]=__uint_as_float(u.z<<16); f[5]=__uint_as_float(u.z&0xffff0000u);
  f[6]=__uint_as_float(u.w<<16); f[7]=__uint_as_float(u.w&0xffff0000u);
}
static __device__ __forceinline__ void gload16(const u16* g, u16* l){
  __builtin_amdgcn_global_load_lds(
      (const __attribute__((address_space(1))) void*)g,
      (__attribute__((address_space(3))) void*)l, 16, 0, 0);
}

#define FENCE() asm volatile("" ::: "memory")
#define BAR() do { FENCE(); __builtin_amdgcn_s_barrier(); FENCE(); } while(0)

// ---------------- fp32 -> bf16 convert: x + 4 weights in ONE launch ----------
__global__ __launch_bounds__(256) void cvt_all(
    const float* __restrict__ x,
    const float* __restrict__ s0, const float* __restrict__ s1,
    const float* __restrict__ s2, const float* __restrict__ s3,
    u16* __restrict__ xb,
    u16* __restrict__ d0, u16* __restrict__ d1,
    u16* __restrict__ d2, u16* __restrict__ d3)
{
  const float* s; u16* d; int bi;
  if (blockIdx.x < 8192) { s = x; d = xb; bi = blockIdx.x; }
  else {
    const int seg = (blockIdx.x - 8192) >> 9;
    bi = (blockIdx.x - 8192) & 511;
    s = seg==0?s0:seg==1?s1:seg==2?s2:s3;
    d = seg==0?d0:seg==1?d1:seg==2?d2:d3;
  }
  const int i = (bi*256 + threadIdx.x) * 8;
  const float4 a = *(const float4*)(s + i);
  const float4 b = *(const float4*)(s + i + 4);
  uint4 o;
  o.x = (u32)f2bf(a.x) | ((u32)f2bf(a.y) << 16);
  o.y = (u32)f2bf(a.z) | ((u32)f2bf(a.w) << 16);
  o.z = (u32)f2bf(b.x) | ((u32)f2bf(b.y) << 16);
  o.w = (u32)f2bf(b.z) | ((u32)f2bf(b.w) << 16);
  *(uint4*)(d + i) = o;
}

// ---------------- 256x256 / BK=64 / 4-phase MFMA GEMM (R3, proven 280us) -----
// Y[M,N] = X[M,K] @ W[N,K]^T + b.  512 threads = 8 waves (2M x 4N), wave tile
// 128x64. LDS ring: slot s: [Al | Ah | Bl | Bh] 16 KB half-buffers.
// T2 swizzle: logical 16B-chunk c of row r at phys chunk c^(r&7); staged via
// linear global_load_lds dest + inverse-swizzled global source.
// Per K-tile u (4 phases), each: {ds_read subtile || stage half-tile -> BAR ->
// setprio(1) 16 MFMA setprio(0) -> BAR}; vmcnt(4) once per tile.
template<bool FUSED>
__global__ __launch_bounds__(512, 2) void gemm256(
    const u16* __restrict__ X, const u16* __restrict__ Wm,
    const float* __restrict__ b0, const float* __restrict__ b1,
    const float* __restrict__ b2,
    void* __restrict__ Y0, void* __restrict__ Y1, void* __restrict__ Y2)
{
  extern __shared__ __align__(16) u16 lds[];   // 131072 B
  const int tid  = threadIdx.x;
  const int lane = tid & 63, w = tid >> 6;
  const int wr = w >> 2, wc = w & 3;           // wave grid 2 x 4
  const int fr = lane & 15, hi = lane >> 4;

  // T1: XCD-aware swizzle (gridDim.x % 8 == 0 here: 768 / 256)
  const int cpx = gridDim.x >> 3;
  const int lin = (blockIdx.x & 7)*cpx + (blockIdx.x >> 3);
  const int bm = lin & 63;                     // bm fastest: B-panel L2 reuse per XCD
  const int bn = lin >> 6;

  const int srow = tid >> 3;                   // 0..63
  const int scc  = (tid & 7) ^ (srow & 7);     // inverse-swizzled source chunk
  const u16* gA = X  + (size_t)(bm*256 + srow)*K_ + scc*8;
  const u16* gB = Wm + (size_t)(bn*256 + srow)*K_ + scc*8;
  u16* const ldst = lds + tid*8;

  auto stageA = [&](int s, int h, int kt){
    const u16* src = gA + (size_t)(h*128)*K_ + kt*64;
    u16* dst = ldst + s*32768 + h*8192;
    gload16(src, dst);
    gload16(src + (size_t)64*K_, dst + 4096);
  };
  auto stageB = [&](int s, int h, int kt){
    const u16* src = gB + (size_t)(h*128)*K_ + kt*64;
    u16* dst = ldst + s*32768 + 16384 + h*8192;
    gload16(src, dst);
    gload16(src + (size_t)64*K_, dst + 4096);
  };

  f32x4 acc[8][4] = {};
  const int cx0 = (hi ^ (fr & 7)) << 3;        // k-half 0 chunk (u16 offset)
  const int cx1 = ((4 + hi) ^ (fr & 7)) << 3;  // k-half 1 chunk
  const int br  = (wc & 1) * 64;               // B local row base

  // prologue, FIFO order: B(0)x4, A(0)x4, B(1)x4  -> wait leaves B(1) in flight
  stageB(0,0,0); stageB(0,1,0);
  stageA(0,0,0); stageA(0,1,0);
  stageB(1,0,1); stageB(1,1,1);
  asm volatile("s_waitcnt vmcnt(4)" ::: "memory");
  BAR();

  #pragma unroll 2
  for (int u = 0; u < NT_; ++u) {
    const int s = u & 1;
    const u16* As = lds + s*32768 + wr*8192;
    const u16* Bs = lds + s*32768 + 16384 + (wc>>1)*8192;

    bf16x8 a[4], bv0[4], bv1[4];

    // ---- ph0: B[k0] + A[i0-3][k0]; stage Al(u+1)
    #pragma unroll
    for (int j = 0; j < 4; ++j) bv0[j] = *(const bf16x8*)&Bs[(br + j*16 + fr)*64 + cx0];
    #pragma unroll
    for (int i = 0; i < 4; ++i) a[i]   = *(const bf16x8*)&As[(i*16 + fr)*64 + cx0];
    if (u + 1 < NT_) stageA(s^1, 0, u+1);
    BAR();
    __builtin_amdgcn_s_setprio(1);
    #pragma unroll
    for (int i = 0; i < 4; ++i)
      #pragma unroll
      for (int j = 0; j < 4; ++j)
        acc[i][j] = __builtin_amdgcn_mfma_f32_16x16x32_bf16(a[i], bv0[j], acc[i][j], 0, 0, 0);
    __builtin_amdgcn_s_setprio(0);
    BAR();

    // ---- ph1: A[i4-7][k0]; stage Ah(u+1)
    #pragma unroll
    for (int i = 0; i < 4; ++i) a[i] = *(const bf16x8*)&As[((4+i)*16 + fr)*64 + cx0];
    if (u + 1 < NT_) stageA(s^1, 1, u+1);
    BAR();
    __builtin_amdgcn_s_setprio(1);
    #pragma unroll
    for (int i = 0; i < 4; ++i)
      #pragma unroll
      for (int j = 0; j < 4; ++j)
        acc[4+i][j] = __builtin_amdgcn_mfma_f32_16x16x32_bf16(a[i], bv0[j], acc[4+i][j], 0, 0, 0);
    __builtin_amdgcn_s_setprio(0);
    BAR();

    // ---- ph2: B[k1] + A[i0-3][k1]
    #pragma unroll
    for (int j = 0; j < 4; ++j) bv1[j] = *(const bf16x8*)&Bs[(br + j*16 + fr)*64 + cx1];
    #pragma unroll
    for (int i = 0; i < 4; ++i) a[i]   = *(const bf16x8*)&As[(i*16 + fr)*64 + cx1];
    BAR();
    __builtin_amdgcn_s_setprio(1);
    #pragma unroll
    for (int i = 0; i < 4; ++i)
      #pragma unroll
      for (int j = 0; j < 4; ++j)
        acc[i][j] = __builtin_amdgcn_mfma_f32_16x16x32_bf16(a[i], bv1[j], acc[i][j], 0, 0, 0);
    __builtin_amdgcn_s_setprio(0);
    BAR();

    // ---- ph3: A[i4-7][k1]; stage Bl,Bh(u+2); counted wait for next tile
    #pragma unroll
    for (int i = 0; i < 4; ++i) a[i] = *(const bf16x8*)&As[((4+i)*16 + fr)*64 + cx1];
    if (u + 2 < NT_) { stageB(s, 0, u+2); stageB(s, 1, u+2); }
    BAR();
    __builtin_amdgcn_s_setprio(1);
    #pragma unroll
    for (int i = 0; i < 4; ++i)
      #pragma unroll
      for (int j = 0; j < 4; ++j)
        acc[4+i][j] = __builtin_amdgcn_mfma_f32_16x16x32_bf16(a[i], bv1[j], acc[4+i][j], 0, 0, 0);
    __builtin_amdgcn_s_setprio(0);
    if (u + 1 < NT_) {
      if (u + 1 == NT_ - 1) asm volatile("s_waitcnt vmcnt(0)" ::: "memory");
      else                  asm volatile("s_waitcnt vmcnt(4)" ::: "memory");
      BAR();
    }
  }

  // epilogue: C/D layout col = lane&15 (n), row = (lane>>4)*4 + reg (m).
  // j innermost: per (i,r) the wave's 4 stores cover one contiguous
  // 128B (bf16) / 256B (fp32) span -> full-line writes, no RMW.
  const int nloc = wc*64 + fr;
  if constexpr (FUSED) {
    const int sel  = bn >> 2;                  // uniform per block
    const int colb = (bn & 3)*256 + nloc;
    const float* bp = (sel == 0 ? b0 : sel == 1 ? b1 : b2);
    u16* Y = (u16*)(sel == 0 ? Y0 : sel == 1 ? Y1 : Y2);
    const bool elu = sel < 2;
    float bb[4];
    #pragma unroll
    for (int j = 0; j < 4; ++j) bb[j] = bp[colb + j*16];
    #pragma unroll
    for (int i = 0; i < 8; ++i) {
      #pragma unroll
      for (int r = 0; r < 4; ++r) {
        const size_t row = (size_t)(bm*256 + wr*128 + i*16 + hi*4 + r);
        u16* yp = Y + row*1024 + colb;
        #pragma unroll
        for (int j = 0; j < 4; ++j) {
          float v = acc[i][j][r] + bb[j];
          if (elu) v = (v > 0.0f) ? (v + 1.0f) : __expf(v);   // elu(x)+1
          yp[j*16] = f2bf(v);
        }
      }
    }
  } else {
    const int n0 = bn*256 + nloc;
    float bb[4];
    #pragma unroll
    for (int j = 0; j < 4; ++j) bb[j] = b0[n0 + j*16];
    float* Y = (float*)Y0;
    #pragma unroll
    for (int i = 0; i < 8; ++i) {
      #pragma unroll
      for (int r = 0; r < 4; ++r) {
        const size_t row = (size_t)(bm*256 + wr*128 + i*16 + hi*4 + r);
        float* yp = Y + row*1024 + n0;
        #pragma unroll
        for (int j = 0; j < 4; ++j)
          yp[j*16] = acc[i][j][r] + bb[j];
      }
    }
  }
}

// ---------------- kv partial (unchanged) -------------------------------------
__global__ __launch_bounds__(256) void kv_partial(
    const u16* __restrict__ Kb, const u16* __restrict__ Vb,
    float* __restrict__ kvp, float* __restrict__ ksp)
{
  const int tid = threadIdx.x;
  const int bh = blockIdx.x;
  const int b = bh >> 4, h = bh & 15;
  const int chunk = blockIdx.y;
  __shared__ float kbuf[32][68];
  __shared__ float vbuf[32][68];
  float acc[4][4] = {};
  float ksl = 0.0f;
  const int d0 = (tid >> 4) << 2, e0 = (tid & 15) << 2;
  const int lrow = tid >> 3, lcol = (tid & 7) << 3;

  for (int s = 0; s < TCH/32; ++s) {
    const int t = chunk*TCH + s*32;
    {
      const size_t base = ((size_t)(b*T_ + t + lrow))*C_ + h*64 + lcol;
      const uint4 ku = *(const uint4*)(Kb + base);
      const uint4 vu = *(const uint4*)(Vb + base);
      float kf[8], vf[8];
      unpack8(ku, kf); unpack8(vu, vf);
      #pragma unroll
      for (int j = 0; j < 8; ++j) { kbuf[lrow][lcol+j] = kf[j]; vbuf[lrow][lcol+j] = vf[j]; }
    }
    __syncthreads();
    if (tid < 64) {
      #pragma unroll
      for (int tt = 0; tt < 32; ++tt) ksl += kbuf[tt][tid];
    }
    #pragma unroll
    for (int tt = 0; tt < 32; ++tt) {
      const float4 ka = *(const float4*)&kbuf[tt][d0];
      const float4 va = *(const float4*)&vbuf[tt][e0];
      const float kr[4] = {ka.x, ka.y, ka.z, ka.w};
      const float vr[4] = {va.x, va.y, va.z, va.w};
      #pragma unroll
      for (int i = 0; i < 4; ++i)
        #pragma unroll
        for (int j = 0; j < 4; ++j)
          acc[i][j] = fmaf(kr[i], vr[j], acc[i][j]);
    }
    __syncthreads();
  }

  float* dst = kvp + ((size_t)(chunk*64 + bh))*4096;
  #pragma unroll
  for (int i = 0; i < 4; ++i)
    *(float4*)&dst[(d0+i)*64 + e0] = make_float4(acc[i][0], acc[i][1], acc[i][2], acc[i][3]);
  if (tid < 64) ksp[((size_t)(chunk*64 + bh))*64 + tid] = ksl;
}

// ---------------- kv reduce -> bf16 kvT[bh][80][64] (row 64 = ksum) ----------
__global__ __launch_bounds__(256) void kv_reduce(
    const float* __restrict__ kvp, const float* __restrict__ ksp,
    u16* __restrict__ kvT)
{
  const int idx = blockIdx.x*256 + threadIdx.x;
  if (idx < 262144) {                          // idx = bh*4096 + d*64 + e
    float s = 0.0f;
    #pragma unroll
    for (int c = 0; c < 8; ++c) s += kvp[(size_t)c*262144 + idx];
    const int bh = idx >> 12, d = (idx >> 6) & 63, e = idx & 63;
    kvT[(size_t)bh*5120 + e*64 + d] = f2bf(s);
  } else if (idx < 266240) {                   // bh*64 + d -> ksum row
    const int i2 = idx - 262144;
    float s = 0.0f;
    #pragma unroll
    for (int c = 0; c < 8; ++c) s += ksp[(size_t)c*4096 + i2];
    const int bh = i2 >> 6, d = i2 & 63;
    kvT[(size_t)bh*5120 + 4096 + d] = f2bf(s);
  } else if (idx < 266240 + 64*15*64) {        // zero rows 65..79
    const int i3 = idx - 266240;
    const int bh = i3 / 960, rd = i3 - bh*960;
    kvT[(size_t)bh*5120 + 4160 + rd] = 0;
  }
}

// ---------------- attn_norm via MFMA -----------------------------------------
// Per (bh, t-tile of 256): attn[t, h*64+e] = (q[t,:] @ kv[:, e]) / den[t],
// den[t] = q[t,:] . ksum.  A = q tile (256x64, staged to LDS, T2-swizzled);
// B-frags read DIRECT from global kvT (10 KB, L2-hot; rows: e<64 = kv^T,
// 64 = ksum, 65..79 = 0).  j=4 quadrant's col 0 = den (rows 64+fr), shfl-
// broadcast from fr==0 lanes.  4 waves, each 64 rows; 40 MFMA/wave; K=64.
__global__ __launch_bounds__(256) void attn_norm_mfma(
    const u16* __restrict__ Qb, const u16* __restrict__ kvT,
    u16* __restrict__ attn)
{
  __shared__ __align__(16) u16 qs[256*64];     // 32 KB
  const int tid = threadIdx.x;
  const int lane = tid & 63, w = tid >> 6;
  const int bh = blockIdx.x;
  const int b = bh >> 4, h = bh & 15;
  const int tt = blockIdx.y;                   // 16 tiles of 256 rows
  const int fr = lane & 15, hi = lane >> 4;

  // stage q tile: linear LDS dest, inverse-swizzled global source (rule #21)
  {
    const int srow = tid >> 3, scc = tid & 7;
    #pragma unroll
    for (int r = 0; r < 8; ++r) {
      const int row = r*32 + srow;
      const u16* src = Qb + ((size_t)(b*T_ + tt*256 + row))*C_ + h*64
                         + ((scc ^ (row & 7)) << 3);
      gload16(src, qs + tid*8 + r*2048);
    }
  }

  // B-fragments direct from global while staging is in flight
  const u16* kvb = kvT + (size_t)bh*5120;
  bf16x8 bv[5][2];
  #pragma unroll
  for (int j = 0; j < 5; ++j) {
    const int row = (j < 4) ? (j*16 + fr) : (64 + fr);
    bv[j][0] = *(const bf16x8*)&kvb[row*64 + hi*8];
    bv[j][1] = *(const bf16x8*)&kvb[row*64 + 32 + hi*8];
  }

  __syncthreads();                             // drains vmcnt: q tile visible

  f32x4 accN[4][4] = {};
  f32x4 accD[4] = {};
  #pragma unroll
  for (int kh = 0; kh < 2; ++kh) {
    const int cx = ((kh*4 + hi) ^ (fr & 7)) << 3;
    bf16x8 a[4];
    #pragma unroll
    for (int i = 0; i < 4; ++i)
      a[i] = *(const bf16x8*)&qs[(w*64 + i*16 + fr)*64 + cx];
    #pragma unroll
    for (int i = 0; i < 4; ++i) {
      #pragma unroll
      for (int j = 0; j < 4; ++j)
        accN[i][j] = __builtin_amdgcn_mfma_f32_16x16x32_bf16(a[i], bv[j][kh], accN[i][j], 0, 0, 0);
      accD[i] = __builtin_amdgcn_mfma_f32_16x16x32_bf16(a[i], bv[4][kh], accD[i], 0, 0, 0);
    }
  }

  // epilogue: den in col 0 (fr==0 lanes) of accD; broadcast within hi-group
  #pragma unroll
  for (int i = 0; i < 4; ++i) {
    #pragma unroll
    for (int r = 0; r < 4; ++r) {
      const float den = __shfl(accD[i][r], lane & 0x30);
      const float inv = 1.0f / fmaxf(den, 1e-6f);
      const size_t row = (size_t)(b*T_ + tt*256 + w*64 + i*16 + hi*4 + r);
      u16* yp = attn + row*1024 + h*64 + fr;
      #pragma unroll
      for (int j = 0; j < 4; ++j)
        yp[j*16] = f2bf(accN[i][j][r] * inv);
    }
  }
}

extern "C" void kernel_launch(void* const* d_in, const int* in_sizes, int n_in,
                              void* d_out, int out_size, void* d_ws, size_t ws_size,
                              hipStream_t stream)
{
  (void)in_sizes; (void)n_in; (void)out_size; (void)ws_size;
  const float* x  = (const float*)d_in[0];
  const float* Wq = (const float*)d_in[1];
  const float* bq = (const float*)d_in[2];
  const float* Wk = (const float*)d_in[3];
  const float* bk = (const float*)d_in[4];
  const float* Wv = (const float*)d_in[5];
  const float* bv = (const float*)d_in[6];
  const float* Wo = (const float*)d_in[7];
  const float* bo = (const float*)d_in[8];
  float* out = (float*)d_out;
  char* ws = (char*)d_ws;

  const size_t MB = 1024*1024;
  u16*   xb   = (u16*)(ws);                       // 32MB
  u16*   wqb  = (u16*)(ws + 32*MB);               // 2MB each; wq..wv = fused [3072,1024]
  u16*   wkb  = (u16*)(ws + 34*MB);
  u16*   wvb  = (u16*)(ws + 36*MB);
  u16*   wob  = (u16*)(ws + 38*MB);
  u16*   q    = (u16*)(ws + 40*MB);               // 32MB
  u16*   k    = (u16*)(ws + 72*MB);               // 32MB
  u16*   v    = (u16*)(ws + 104*MB);              // 32MB
  float* kvp  = (float*)(ws + 136*MB);            // 8MB
  float* ksp  = (float*)(ws + 144*MB);            // 128KB
  u16*   kvT  = (u16*)(ws + 144*MB + 131072);     // 640KB bf16 [64][80][64]
  u16*   attn = xb;  // xb dead after the fused QKV GEMM

  static bool s_attr_done = false;
  if (!s_attr_done) {
    (void)hipFuncSetAttribute(reinterpret_cast<const void*>(gemm256<true>),
                              hipFuncAttributeMaxDynamicSharedMemorySize, 131072);
    (void)hipFuncSetAttribute(reinterpret_cast<const void*>(gemm256<false>),
                              hipFuncAttributeMaxDynamicSharedMemorySize, 131072);
    s_attr_done = true;
  }

  dim3 blk(256);
  // x: 8192 blocks; 4 weights: 512 blocks each
  cvt_all<<<dim3(8192 + 4*512), blk, 0, stream>>>(
      x, Wq, Wk, Wv, Wo, xb, wqb, wkb, wvb, wob);

  // fused QKV projection: Y[16384, 3072] split into q/k/v, ELU+1 on q,k
  gemm256<true><<<dim3(64*12), dim3(512), 131072, stream>>>(
      xb, wqb, bq, bk, bv, q, k, v);

  kv_partial<<<dim3(B_*H_, T_/TCH), blk, 0, stream>>>(k, v, kvp, ksp);
  kv_reduce<<<dim3(1280), blk, 0, stream>>>(kvp, ksp, kvT);
  attn_norm_mfma<<<dim3(B_*H_, T_/256), blk, 0, stream>>>(q, kvT, attn);

  // output projection: fp32 out
  gemm256<false><<<dim3(64*4), dim3(512), 131072, stream>>>(
      attn, wob, bo, bo, bo, out, out, out);
}

// Round 5
// 220.878 us; speedup vs baseline: 1.5379x; 1.0267x over previous
//
#include <hip/hip_runtime.h>
#include <hip/hip_bf16.h>
#include <stdint.h>

// Round 6: attack the per-tile staging-latency stall in the proven 4-phase GEMM.
//  - 3-deep A ring + 2-deep B ring = 160 KiB LDS (AITER fmha precedent, m243).
//    A(v+2)/B(v+2) both staged during tile v -> ~7.5 phases of slack >> HBM
//    latency; vmcnt(8) per tile (2 full tiles in flight, FIFO A,A,B,B).
//  - Patch-based XCD mapping (4bm x 4bn = 4 MB working set per patch, fits
//    one XCD L2), bijective for both grids.
//  - B staging spread across ph2/ph3 (1 half-tile per phase).
// attn chain (MFMA attn_norm, bf16 kvT, merged cvt) unchanged from R5.
//
// ws layout (bytes):
//   xb   : [0, 32MB)  bf16 [M, C]   (reused as attn)
//   wqb  : 32MB + 2MB each: wkb, wvb, wob   (wq..wv contiguous = fused [3C, C])
//   q    : 40MB  k : 72MB  v : 104MB   bf16 [M, C]
//   kvp  : 136MB f32 [8][64][64][64];  ksp : +8MB f32 [8][64][64]
//   kvT  : 144MB+128KB  bf16 [64][80][64]  (640 KB)

#define B_ 4
#define T_ 4096
#define C_ 1024
#define H_ 16
#define D_ 64
#define M_ (B_*T_)
#define TCH 512
#define K_ 1024
#define NT_ (K_/64)          // 16 K-tiles of BK=64

using u16 = unsigned short;
using u32 = unsigned int;

typedef __attribute__((ext_vector_type(8))) short bf16x8;
typedef __attribute__((ext_vector_type(4))) float f32x4;

static __device__ __forceinline__ u16 f2bf(float f){
  u32 u = __float_as_uint(f);
  u32 r = (u + 0x7fffu + ((u >> 16) & 1u)) >> 16;   // RNE, no NaN here
  return (u16)r;
}
static __device__ __forceinline__ void unpack8(uint4 u, float* f){
  f[0]=__uint_as_float(u.x<<16); f[1]=__uint_as_float(u.x&0xffff0000u);
  f[2]=__uint_as_float(u.y<<16); f[3]=__uint_as_float(u.y&0xffff0000u);
  f[4]=__uint_as_float(u.z<<16); f[5]=__uint_as_float(u.z&0xffff0000u);
  f[6]=__uint_as_float(u.w<<16); f[7]=__uint_as_float(u.w&0xffff0000u);
}
static __device__ __forceinline__ void gload16(const u16* g, u16* l){
  __builtin_amdgcn_global_load_lds(
      (const __attribute__((address_space(1))) void*)g,
      (__attribute__((address_space(3))) void*)l, 16, 0, 0);
}

#define FENCE() asm volatile("" ::: "memory")
#define BAR() do { FENCE(); __builtin_amdgcn_s_barrier(); FENCE(); } while(0)

// ---------------- fp32 -> bf16 convert: x + 4 weights in ONE launch ----------
__global__ __launch_bounds__(256) void cvt_all(
    const float* __restrict__ x,
    const float* __restrict__ s0, const float* __restrict__ s1,
    const float* __restrict__ s2, const float* __restrict__ s3,
    u16* __restrict__ xb,
    u16* __restrict__ d0, u16* __restrict__ d1,
    u16* __restrict__ d2, u16* __restrict__ d3)
{
  const float* s; u16* d; int bi;
  if (blockIdx.x < 8192) { s = x; d = xb; bi = blockIdx.x; }
  else {
    const int seg = (blockIdx.x - 8192) >> 9;
    bi = (blockIdx.x - 8192) & 511;
    s = seg==0?s0:seg==1?s1:seg==2?s2:s3;
    d = seg==0?d0:seg==1?d1:seg==2?d2:d3;
  }
  const int i = (bi*256 + threadIdx.x) * 8;
  const float4 a = *(const float4*)(s + i);
  const float4 b = *(const float4*)(s + i + 4);
  uint4 o;
  o.x = (u32)f2bf(a.x) | ((u32)f2bf(a.y) << 16);
  o.y = (u32)f2bf(a.z) | ((u32)f2bf(a.w) << 16);
  o.z = (u32)f2bf(b.x) | ((u32)f2bf(b.y) << 16);
  o.w = (u32)f2bf(b.z) | ((u32)f2bf(b.w) << 16);
  *(uint4*)(d + i) = o;
}

// ---------------- 256x256 / BK=64 / 4-phase MFMA GEMM, 3-deep A ring ---------
// Y[M,N] = X[M,K] @ W[N,K]^T + b.  512 threads = 8 waves (2M x 4N), wave tile
// 128x64.  LDS 160 KiB: A slots 0..2 (32 KB each, u16 off a*16384),
// B slots 0..1 (32 KB each, u16 off 49152 + b*16384); halves +8192 u16.
// T2 swizzle: logical 16B-chunk c of row r at phys chunk c^(r&7); staged via
// linear global_load_lds dest + inverse-swizzled global source.
// Per K-tile v (4 phases, each {reads || stage 1 half -> BAR -> 16 MFMA -> BAR}):
//   ph0: B[k0]+A[0-3][k0]; stage Alo(v+2)   ph1: A[4-7][k0]; stage Ahi(v+2)
//   ph2: B[k1]+A[0-3][k1]; stage Blo(v+2)   ph3: A[4-7][k1]; stage Bhi(v+2)
//   end: vmcnt(8) (drains A(v+1),B(v+1); leaves A/B(v+2) in flight); BAR
// WAR: A slot (v+2)%3 last read tile v-1 (reads complete before its closing
// BAR); B slot (v+2)%2 = v%2 last read at ph2 of v (< ph2 closing BAR < ph3).
template<bool FUSED>
__global__ __launch_bounds__(512, 2) void gemm256(
    const u16* __restrict__ X, const u16* __restrict__ Wm,
    const float* __restrict__ b0, const float* __restrict__ b1,
    const float* __restrict__ b2,
    void* __restrict__ Y0, void* __restrict__ Y1, void* __restrict__ Y2)
{
  extern __shared__ __align__(16) u16 lds[];   // 163840 B
  const int tid  = threadIdx.x;
  const int lane = tid & 63, w = tid >> 6;
  const int wr = w >> 2, wc = w & 3;           // wave grid 2 x 4
  const int fr = lane & 15, hi = lane >> 4;

  // patch-based XCD mapping: 4bm x 4bn patches (2MB x-panel + 2MB W-panel =
  // fits one XCD L2), patches assigned contiguously per XCD. Bijective:
  // FUSED grid 768 = 8 XCD * 6 patches * 16; !FUSED 256 = 8 * 2 * 16.
  const int xcd = blockIdx.x & 7;
  const int r   = blockIdx.x >> 3;
  const int ppx = gridDim.x >> 7;              // patches per XCD (6 or 2)
  const int patchIdx = xcd * ppx + (r >> 4);
  const int wi = r & 15;
  const int pm = FUSED ? (patchIdx & 15) : patchIdx;
  const int pn = FUSED ? (patchIdx >> 4) : 0;
  const int bm = pm*4 + (wi & 3);
  const int bn = pn*4 + (wi >> 2);

  const int srow = tid >> 3;                   // 0..63
  const int scc  = (tid & 7) ^ (srow & 7);     // inverse-swizzled source chunk
  const u16* gA = X  + (size_t)(bm*256 + srow)*K_ + scc*8;
  const u16* gB = Wm + (size_t)(bn*256 + srow)*K_ + scc*8;

  auto stageA = [&](int slot, int h, int kt){
    const u16* src = gA + (size_t)(h*128)*K_ + kt*64;
    u16* dst = lds + slot*16384 + h*8192 + tid*8;
    gload16(src, dst);
    gload16(src + (size_t)64*K_, dst + 4096);
  };
  auto stageB = [&](int slot, int h, int kt){
    const u16* src = gB + (size_t)(h*128)*K_ + kt*64;
    u16* dst = lds + 49152 + slot*16384 + h*8192 + tid*8;
    gload16(src, dst);
    gload16(src + (size_t)64*K_, dst + 4096);
  };

  f32x4 acc[8][4] = {};
  const int cx0 = (hi ^ (fr & 7)) << 3;        // k-half 0 chunk (u16 offset)
  const int cx1 = ((4 + hi) ^ (fr & 7)) << 3;  // k-half 1 chunk
  const int br  = (wc & 1) * 64;               // B local row base

  // prologue: A(0), B(0), A(1), B(1) in FIFO order; vmcnt(8) drains tile 0
  stageA(0,0,0); stageA(0,1,0);
  stageB(0,0,0); stageB(0,1,0);
  stageA(1,0,1); stageA(1,1,1);
  stageB(1,0,1); stageB(1,1,1);
  asm volatile("s_waitcnt vmcnt(8)" ::: "memory");
  BAR();

  int aslot = 0;                               // = v % 3
  #pragma unroll 2
  for (int v = 0; v < NT_; ++v) {
    const int bslot  = v & 1;
    const int astage = (aslot == 0) ? 2 : aslot - 1;   // (v+2) % 3
    const bool more  = (v + 2 < NT_);
    const u16* As = lds + aslot*16384 + wr*8192;
    const u16* Bs = lds + 49152 + bslot*16384 + (wc>>1)*8192;

    bf16x8 a[4], bv0[4], bv1[4];

    // ---- ph0: B[k0] + A[0-3][k0]; stage Alo(v+2)
    #pragma unroll
    for (int j = 0; j < 4; ++j) bv0[j] = *(const bf16x8*)&Bs[(br + j*16 + fr)*64 + cx0];
    #pragma unroll
    for (int i = 0; i < 4; ++i) a[i]   = *(const bf16x8*)&As[(i*16 + fr)*64 + cx0];
    if (more) stageA(astage, 0, v+2);
    BAR();
    __builtin_amdgcn_s_setprio(1);
    #pragma unroll
    for (int i = 0; i < 4; ++i)
      #pragma unroll
      for (int j = 0; j < 4; ++j)
        acc[i][j] = __builtin_amdgcn_mfma_f32_16x16x32_bf16(a[i], bv0[j], acc[i][j], 0, 0, 0);
    __builtin_amdgcn_s_setprio(0);
    BAR();

    // ---- ph1: A[4-7][k0]; stage Ahi(v+2)
    #pragma unroll
    for (int i = 0; i < 4; ++i) a[i] = *(const bf16x8*)&As[((4+i)*16 + fr)*64 + cx0];
    if (more) stageA(astage, 1, v+2);
    BAR();
    __builtin_amdgcn_s_setprio(1);
    #pragma unroll
    for (int i = 0; i < 4; ++i)
      #pragma unroll
      for (int j = 0; j < 4; ++j)
        acc[4+i][j] = __builtin_amdgcn_mfma_f32_16x16x32_bf16(a[i], bv0[j], acc[4+i][j], 0, 0, 0);
    __builtin_amdgcn_s_setprio(0);
    BAR();

    // ---- ph2: B[k1] + A[0-3][k1]; stage Blo(v+2)
    #pragma unroll
    for (int j = 0; j < 4; ++j) bv1[j] = *(const bf16x8*)&Bs[(br + j*16 + fr)*64 + cx1];
    #pragma unroll
    for (int i = 0; i < 4; ++i) a[i]   = *(const bf16x8*)&As[(i*16 + fr)*64 + cx1];
    if (more) stageB(bslot, 0, v+2);
    BAR();
    __builtin_amdgcn_s_setprio(1);
    #pragma unroll
    for (int i = 0; i < 4; ++i)
      #pragma unroll
      for (int j = 0; j < 4; ++j)
        acc[i][j] = __builtin_amdgcn_mfma_f32_16x16x32_bf16(a[i], bv1[j], acc[i][j], 0, 0, 0);
    __builtin_amdgcn_s_setprio(0);
    BAR();

    // ---- ph3: A[4-7][k1]; stage Bhi(v+2); counted wait for next tile
    #pragma unroll
    for (int i = 0; i < 4; ++i) a[i] = *(const bf16x8*)&As[((4+i)*16 + fr)*64 + cx1];
    if (more) stageB(bslot, 1, v+2);
    BAR();
    __builtin_amdgcn_s_setprio(1);
    #pragma unroll
    for (int i = 0; i < 4; ++i)
      #pragma unroll
      for (int j = 0; j < 4; ++j)
        acc[4+i][j] = __builtin_amdgcn_mfma_f32_16x16x32_bf16(a[i], bv1[j], acc[4+i][j], 0, 0, 0);
    __builtin_amdgcn_s_setprio(0);
    if (v + 1 < NT_) {
      if (more) asm volatile("s_waitcnt vmcnt(8)" ::: "memory");
      else      asm volatile("s_waitcnt vmcnt(0)" ::: "memory");
      BAR();
    }
    aslot = (aslot == 2) ? 0 : aslot + 1;
  }

  // epilogue: C/D layout col = lane&15 (n), row = (lane>>4)*4 + reg (m).
  // j innermost: per (i,r) the wave's 4 stores cover one contiguous
  // 128B (bf16) / 256B (fp32) span -> full-line writes, no RMW.
  const int nloc = wc*64 + fr;
  if constexpr (FUSED) {
    const int sel  = bn >> 2;                  // uniform per block
    const int colb = (bn & 3)*256 + nloc;
    const float* bp = (sel == 0 ? b0 : sel == 1 ? b1 : b2);
    u16* Y = (u16*)(sel == 0 ? Y0 : sel == 1 ? Y1 : Y2);
    const bool elu = sel < 2;
    float bb[4];
    #pragma unroll
    for (int j = 0; j < 4; ++j) bb[j] = bp[colb + j*16];
    #pragma unroll
    for (int i = 0; i < 8; ++i) {
      #pragma unroll
      for (int r2 = 0; r2 < 4; ++r2) {
        const size_t row = (size_t)(bm*256 + wr*128 + i*16 + hi*4 + r2);
        u16* yp = Y + row*1024 + colb;
        #pragma unroll
        for (int j = 0; j < 4; ++j) {
          float vv = acc[i][j][r2] + bb[j];
          if (elu) vv = (vv > 0.0f) ? (vv + 1.0f) : __expf(vv);   // elu(x)+1
          yp[j*16] = f2bf(vv);
        }
      }
    }
  } else {
    const int n0 = bn*256 + nloc;
    float bb[4];
    #pragma unroll
    for (int j = 0; j < 4; ++j) bb[j] = b0[n0 + j*16];
    float* Y = (float*)Y0;
    #pragma unroll
    for (int i = 0; i < 8; ++i) {
      #pragma unroll
      for (int r2 = 0; r2 < 4; ++r2) {
        const size_t row = (size_t)(bm*256 + wr*128 + i*16 + hi*4 + r2);
        float* yp = Y + row*1024 + n0;
        #pragma unroll
        for (int j = 0; j < 4; ++j)
          yp[j*16] = acc[i][j][r2] + bb[j];
      }
    }
  }
}

// ---------------- kv partial (unchanged) -------------------------------------
__global__ __launch_bounds__(256) void kv_partial(
    const u16* __restrict__ Kb, const u16* __restrict__ Vb,
    float* __restrict__ kvp, float* __restrict__ ksp)
{
  const int tid = threadIdx.x;
  const int bh = blockIdx.x;
  const int b = bh >> 4, h = bh & 15;
  const int chunk = blockIdx.y;
  __shared__ float kbuf[32][68];
  __shared__ float vbuf[32][68];
  float acc[4][4] = {};
  float ksl = 0.0f;
  const int d0 = (tid >> 4) << 2, e0 = (tid & 15) << 2;
  const int lrow = tid >> 3, lcol = (tid & 7) << 3;

  for (int s = 0; s < TCH/32; ++s) {
    const int t = chunk*TCH + s*32;
    {
      const size_t base = ((size_t)(b*T_ + t + lrow))*C_ + h*64 + lcol;
      const uint4 ku = *(const uint4*)(Kb + base);
      const uint4 vu = *(const uint4*)(Vb + base);
      float kf[8], vf[8];
      unpack8(ku, kf); unpack8(vu, vf);
      #pragma unroll
      for (int j = 0; j < 8; ++j) { kbuf[lrow][lcol+j] = kf[j]; vbuf[lrow][lcol+j] = vf[j]; }
    }
    __syncthreads();
    if (tid < 64) {
      #pragma unroll
      for (int tt = 0; tt < 32; ++tt) ksl += kbuf[tt][tid];
    }
    #pragma unroll
    for (int tt = 0; tt < 32; ++tt) {
      const float4 ka = *(const float4*)&kbuf[tt][d0];
      const float4 va = *(const float4*)&vbuf[tt][e0];
      const float kr[4] = {ka.x, ka.y, ka.z, ka.w};
      const float vr[4] = {va.x, va.y, va.z, va.w};
      #pragma unroll
      for (int i = 0; i < 4; ++i)
        #pragma unroll
        for (int j = 0; j < 4; ++j)
          acc[i][j] = fmaf(kr[i], vr[j], acc[i][j]);
    }
    __syncthreads();
  }

  float* dst = kvp + ((size_t)(chunk*64 + bh))*4096;
  #pragma unroll
  for (int i = 0; i < 4; ++i)
    *(float4*)&dst[(d0+i)*64 + e0] = make_float4(acc[i][0], acc[i][1], acc[i][2], acc[i][3]);
  if (tid < 64) ksp[((size_t)(chunk*64 + bh))*64 + tid] = ksl;
}

// ---------------- kv reduce -> bf16 kvT[bh][80][64] (row 64 = ksum) ----------
__global__ __launch_bounds__(256) void kv_reduce(
    const float* __restrict__ kvp, const float* __restrict__ ksp,
    u16* __restrict__ kvT)
{
  const int idx = blockIdx.x*256 + threadIdx.x;
  if (idx < 262144) {                          // idx = bh*4096 + d*64 + e
    float s = 0.0f;
    #pragma unroll
    for (int c = 0; c < 8; ++c) s += kvp[(size_t)c*262144 + idx];
    const int bh = idx >> 12, d = (idx >> 6) & 63, e = idx & 63;
    kvT[(size_t)bh*5120 + e*64 + d] = f2bf(s);
  } else if (idx < 266240) {                   // bh*64 + d -> ksum row
    const int i2 = idx - 262144;
    float s = 0.0f;
    #pragma unroll
    for (int c = 0; c < 8; ++c) s += ksp[(size_t)c*4096 + i2];
    const int bh = i2 >> 6, d = i2 & 63;
    kvT[(size_t)bh*5120 + 4096 + d] = f2bf(s);
  } else if (idx < 266240 + 64*15*64) {        // zero rows 65..79
    const int i3 = idx - 266240;
    const int bh = i3 / 960, rd = i3 - bh*960;
    kvT[(size_t)bh*5120 + 4160 + rd] = 0;
  }
}

// ---------------- attn_norm via MFMA (unchanged from R5) ---------------------
__global__ __launch_bounds__(256) void attn_norm_mfma(
    const u16* __restrict__ Qb, const u16* __restrict__ kvT,
    u16* __restrict__ attn)
{
  __shared__ __align__(16) u16 qs[256*64];     // 32 KB
  const int tid = threadIdx.x;
  const int lane = tid & 63, w = tid >> 6;
  const int bh = blockIdx.x;
  const int b = bh >> 4, h = bh & 15;
  const int tt = blockIdx.y;                   // 16 tiles of 256 rows
  const int fr = lane & 15, hi = lane >> 4;

  // stage q tile: linear LDS dest, inverse-swizzled global source (rule #21)
  {
    const int srow = tid >> 3, scc = tid & 7;
    #pragma unroll
    for (int r = 0; r < 8; ++r) {
      const int row = r*32 + srow;
      const u16* src = Qb + ((size_t)(b*T_ + tt*256 + row))*C_ + h*64
                         + ((scc ^ (row & 7)) << 3);
      gload16(src, qs + tid*8 + r*2048);
    }
  }

  // B-fragments direct from global while staging is in flight
  const u16* kvb = kvT + (size_t)bh*5120;
  bf16x8 bv[5][2];
  #pragma unroll
  for (int j = 0; j < 5; ++j) {
    const int row = (j < 4) ? (j*16 + fr) : (64 + fr);
    bv[j][0] = *(const bf16x8*)&kvb[row*64 + hi*8];
    bv[j][1] = *(const bf16x8*)&kvb[row*64 + 32 + hi*8];
  }

  __syncthreads();                             // drains vmcnt: q tile visible

  f32x4 accN[4][4] = {};
  f32x4 accD[4] = {};
  #pragma unroll
  for (int kh = 0; kh < 2; ++kh) {
    const int cx = ((kh*4 + hi) ^ (fr & 7)) << 3;
    bf16x8 a[4];
    #pragma unroll
    for (int i = 0; i < 4; ++i)
      a[i] = *(const bf16x8*)&qs[(w*64 + i*16 + fr)*64 + cx];
    #pragma unroll
    for (int i = 0; i < 4; ++i) {
      #pragma unroll
      for (int j = 0; j < 4; ++j)
        accN[i][j] = __builtin_amdgcn_mfma_f32_16x16x32_bf16(a[i], bv[j][kh], accN[i][j], 0, 0, 0);
      accD[i] = __builtin_amdgcn_mfma_f32_16x16x32_bf16(a[i], bv[4][kh], accD[i], 0, 0, 0);
    }
  }

  // epilogue: den in col 0 (fr==0 lanes) of accD; broadcast within hi-group
  #pragma unroll
  for (int i = 0; i < 4; ++i) {
    #pragma unroll
    for (int r = 0; r < 4; ++r) {
      const float den = __shfl(accD[i][r], lane & 0x30);
      const float inv = 1.0f / fmaxf(den, 1e-6f);
      const size_t row = (size_t)(b*T_ + tt*256 + w*64 + i*16 + hi*4 + r);
      u16* yp = attn + row*1024 + h*64 + fr;
      #pragma unroll
      for (int j = 0; j < 4; ++j)
        yp[j*16] = f2bf(accN[i][j][r] * inv);
    }
  }
}

extern "C" void kernel_launch(void* const* d_in, const int* in_sizes, int n_in,
                              void* d_out, int out_size, void* d_ws, size_t ws_size,
                              hipStream_t stream)
{
  (void)in_sizes; (void)n_in; (void)out_size; (void)ws_size;
  const float* x  = (const float*)d_in[0];
  const float* Wq = (const float*)d_in[1];
  const float* bq = (const float*)d_in[2];
  const float* Wk = (const float*)d_in[3];
  const float* bk = (const float*)d_in[4];
  const float* Wv = (const float*)d_in[5];
  const float* bv = (const float*)d_in[6];
  const float* Wo = (const float*)d_in[7];
  const float* bo = (const float*)d_in[8];
  float* out = (float*)d_out;
  char* ws = (char*)d_ws;

  const size_t MB = 1024*1024;
  u16*   xb   = (u16*)(ws);                       // 32MB
  u16*   wqb  = (u16*)(ws + 32*MB);               // 2MB each; wq..wv = fused [3072,1024]
  u16*   wkb  = (u16*)(ws + 34*MB);
  u16*   wvb  = (u16*)(ws + 36*MB);
  u16*   wob  = (u16*)(ws + 38*MB);
  u16*   q    = (u16*)(ws + 40*MB);               // 32MB
  u16*   k    = (u16*)(ws + 72*MB);               // 32MB
  u16*   v    = (u16*)(ws + 104*MB);              // 32MB
  float* kvp  = (float*)(ws + 136*MB);            // 8MB
  float* ksp  = (float*)(ws + 144*MB);            // 128KB
  u16*   kvT  = (u16*)(ws + 144*MB + 131072);     // 640KB bf16 [64][80][64]
  u16*   attn = xb;  // xb dead after the fused QKV GEMM

  static bool s_attr_done = false;
  if (!s_attr_done) {
    (void)hipFuncSetAttribute(reinterpret_cast<const void*>(gemm256<true>),
                              hipFuncAttributeMaxDynamicSharedMemorySize, 163840);
    (void)hipFuncSetAttribute(reinterpret_cast<const void*>(gemm256<false>),
                              hipFuncAttributeMaxDynamicSharedMemorySize, 163840);
    s_attr_done = true;
  }

  dim3 blk(256);
  // x: 8192 blocks; 4 weights: 512 blocks each
  cvt_all<<<dim3(8192 + 4*512), blk, 0, stream>>>(
      x, Wq, Wk, Wv, Wo, xb, wqb, wkb, wvb, wob);

  // fused QKV projection: Y[16384, 3072] split into q/k/v, ELU+1 on q,k
  gemm256<true><<<dim3(64*12), dim3(512), 163840, stream>>>(
      xb, wqb, bq, bk, bv, q, k, v);

  kv_partial<<<dim3(B_*H_, T_/TCH), blk, 0, stream>>>(k, v, kvp, ksp);
  kv_reduce<<<dim3(1280), blk, 0, stream>>>(kvp, ksp, kvT);
  attn_norm_mfma<<<dim3(B_*H_, T_/256), blk, 0, stream>>>(q, kvT, attn);

  // output projection: fp32 out
  gemm256<false><<<dim3(64*4), dim3(512), 163840, stream>>>(
      attn, wob, bo, bo, bo, out, out, out);
}